// Round 4
// baseline (283.885 us; speedup 1.0000x reference)
//
#include <hip/hip_runtime.h>
#include <hip/hip_bf16.h>
#include <math.h>

// Problem constants
#define B_   16
#define IC_  32
#define HW_  128
#define NF_  8
#define OC_  64
#define K_   5
#define GRP_ 8
#define COTOT_ (OC_ * GRP_)   // 512
#define XTH  132              // padded spatial (128 + 2*2)
#define TAPSTRIDE (COTOT_ * IC_)   // elements per tap in wt

typedef short  short8  __attribute__((ext_vector_type(8)));
typedef unsigned short ushort8 __attribute__((ext_vector_type(8)));
typedef float  f32x4   __attribute__((ext_vector_type(4)));

static __device__ inline unsigned short f2bf(float f) {
    unsigned u = __builtin_bit_cast(unsigned, f);
    unsigned r = (u + 0x7FFFu + ((u >> 16) & 1u)) >> 16;
    return (unsigned short)r;
}

// async global -> LDS, 16 bytes per lane
__device__ __forceinline__ void gload16(void* lds, const void* g) {
    __builtin_amdgcn_global_load_lds(
        (const __attribute__((address_space(1))) unsigned int*)g,
        (__attribute__((address_space(3))) unsigned int*)lds, 16, 0, 0);
}

// ---------------------------------------------------------------------------
// Kernel 1: x NCHW fp32 -> padded NHWC bf16   xt[b][hp][wp][ic]
// ---------------------------------------------------------------------------
__global__ __launch_bounds__(256) void xform_kernel(
    const float* __restrict__ x, unsigned short* __restrict__ xt) {
    int idx = blockIdx.x * blockDim.x + threadIdx.x;
    const int TOT = B_ * XTH * XTH;
    if (idx >= TOT) return;
    int wp = idx % XTH;
    int t  = idx / XTH;
    int hp = t % XTH;
    int b  = t / XTH;

    unsigned short vals[IC_];
    bool interior = (hp >= 2) && (hp < 2 + HW_) && (wp >= 2) && (wp < 2 + HW_);
    if (interior) {
        const float* xb = x + ((size_t)b * IC_) * (HW_ * HW_) + (hp - 2) * HW_ + (wp - 2);
        #pragma unroll
        for (int ic = 0; ic < IC_; ++ic)
            vals[ic] = f2bf(xb[(size_t)ic * (HW_ * HW_)]);
    } else {
        #pragma unroll
        for (int ic = 0; ic < IC_; ++ic) vals[ic] = 0;
    }
    ushort8* dst = (ushort8*)(xt + (size_t)idx * IC_);
    #pragma unroll
    for (int c = 0; c < 4; ++c) {
        ushort8 v;
        #pragma unroll
        for (int j = 0; j < 8; ++j) v[j] = vals[c * 8 + j];
        dst[c] = v;
    }
}

// ---------------------------------------------------------------------------
// Kernel 2: rotated+mixed weights -> bf16, layout wt[tap25][co512][ic32]
// ---------------------------------------------------------------------------
__global__ __launch_bounds__(256) void build_w_kernel(
    const float* __restrict__ kern,
    const float* __restrict__ relaxed,
    unsigned short* __restrict__ wt) {
    int idx = blockIdx.x * blockDim.x + threadIdx.x;
    const int TOT = 25 * COTOT_ * IC_;
    if (idx >= TOT) return;
    int ic = idx & (IC_ - 1);
    int t  = idx >> 5;
    int co = t & (COTOT_ - 1);
    int e  = t >> 9;            // ky*5+kx
    int a  = co & (GRP_ - 1);
    int o  = co >> 3;
    int i  = e / K_;            // ky
    int j  = e - i * K_;        // kx

    float theta = -6.283185307179586f / (float)GRP_ * (float)a;
    float cth = cosf(theta), sth = sinf(theta);
    float bx = (2.0f * (float)j + 1.0f) / (float)K_ - 1.0f;
    float by = (2.0f * (float)i + 1.0f) / (float)K_ - 1.0f;
    float gx = cth * bx - sth * by;
    float gy = sth * bx + cth * by;
    float ix = ((gx + 1.0f) * (float)K_ - 1.0f) * 0.5f;
    float iy = ((gy + 1.0f) * (float)K_ - 1.0f) * 0.5f;
    float x0 = floorf(ix), y0 = floorf(iy);
    float wx1 = ix - x0, wy1 = iy - y0;
    float wx0 = 1.0f - wx1, wy0 = 1.0f - wy1;

    float xs2[2]  = {x0, x0 + 1.0f};
    float ys2[2]  = {y0, y0 + 1.0f};
    float wxs[2] = {wx0, wx1};
    float wys[2] = {wy0, wy1};

    float tw[4];
    int   tyc[4], txc[4];
    #pragma unroll
    for (int dy = 0; dy < 2; ++dy) {
        #pragma unroll
        for (int dx = 0; dx < 2; ++dx) {
            float xx = xs2[dx], yy = ys2[dy];
            bool valid = (xx >= 0.0f) && (xx < (float)K_) &&
                         (yy >= 0.0f) && (yy < (float)K_);
            int tp = dy * 2 + dx;
            tw[tp]  = wys[dy] * wxs[dx] * (valid ? 1.0f : 0.0f);
            txc[tp] = (int)fminf(fmaxf(xx, 0.0f), (float)(K_ - 1));
            tyc[tp] = (int)fminf(fmaxf(yy, 0.0f), (float)(K_ - 1));
        }
    }

    float acc = 0.0f;
    #pragma unroll
    for (int n = 0; n < NF_; ++n) {
        const float* kb = kern + ((size_t)((n * OC_ + o) * IC_ + ic)) * (K_ * K_);
        float v = 0.0f;
        #pragma unroll
        for (int tp = 0; tp < 4; ++tp)
            v += kb[tyc[tp] * K_ + txc[tp]] * tw[tp];
        acc += relaxed[n * GRP_ + a] * v;
    }
    wt[idx] = f2bf(acc);
}

// ---------------------------------------------------------------------------
// Kernel 3: MFMA implicit-GEMM conv + leaky relu
// block = 256 thr (4 waves) = 128 co x 2 h x 128 w
// wave  = 8x4 fragments of 16x16: 128 co x 64 w at one h row
// Weights: global -> VGPR directly (all waves share the same 8 KB/tap slice,
//          L1/L2-served), double-buffered in registers across taps.
// x halo: staged in LDS once; tap loop is BARRIER-FREE.
// ---------------------------------------------------------------------------
__global__ __launch_bounds__(256, 2) void conv_mfma_kernel(
    const unsigned short* __restrict__ xt,
    const unsigned short* __restrict__ wt,
    float* __restrict__ out) {
    // x tile: [chunk4][row6][w132][8ic] bf16 = 50688 B, staged once
    __shared__ __align__(16) unsigned short xs[4 * 6 * XTH * 8];

    int tid  = threadIdx.x;
    int lane = tid & 63;
    int wv   = tid >> 6;          // 0..3
    int l15  = lane & 15;
    int l4   = lane >> 4;         // 0..3 (k-chunk)
    int hr   = wv >> 1;           // wave's output row (0/1)
    int wn   = wv & 1;            // wave's w half (0/1)

    int hp = blockIdx.x;          // 0..63 -> rows 2*hp, 2*hp+1
    int b  = blockIdx.y;
    int cg = blockIdx.z;          // slowest: same-cg blocks cluster per XCD
    int cobase = cg * 128;
    int h0 = hp * 2;

    // ---- stage x halo once (async): rows h0..h0+5, full padded width ----
    {
        const unsigned short* xb = xt + (((size_t)b * XTH + h0) * XTH) * IC_;
        for (int i = 0; i < 13; ++i) {
            int s = i * 256 + tid;          // slot: 16B each, 3168 total
            if (s < 3168) {
                int ch  = s / (6 * XTH);
                int rem = s - ch * (6 * XTH);
                int row = rem / XTH;
                int w   = rem - row * XTH;
                gload16(&xs[s * 8], xb + ((size_t)row * XTH + w) * IC_ + ch * 8);
            }
        }
    }

    // per-lane weight base: lane l reads A-frag bytes for co=cobase+m*16+l15, k=l4*8..
    const unsigned short* wl = wt + (size_t)(cobase + l15) * IC_ + l4 * 8;

    // ---- preload tap 0 weights into af0 ----
    short8 af0[8], af1[8];
    #pragma unroll
    for (int m = 0; m < 8; ++m)
        af0[m] = *(const short8*)(wl + (size_t)m * 16 * IC_);

    f32x4 acc[8][4];
    #pragma unroll
    for (int m = 0; m < 8; ++m)
        #pragma unroll
        for (int n = 0; n < 4; ++n) acc[m][n] = (f32x4)(0.0f);

    __syncthreads();   // x halo visible to all waves (drains vmcnt too)

    #pragma unroll
    for (int t = 0; t < 25; ++t) {
        // ---- prefetch next tap's weights into the other register set ----
        if (t < 24) {
            const unsigned short* wn_ = wl + (size_t)(t + 1) * TAPSTRIDE;
            if (t & 1) {
                #pragma unroll
                for (int m = 0; m < 8; ++m)
                    af0[m] = *(const short8*)(wn_ + (size_t)m * 16 * IC_);
            } else {
                #pragma unroll
                for (int m = 0; m < 8; ++m)
                    af1[m] = *(const short8*)(wn_ + (size_t)m * 16 * IC_);
            }
        }
        const int ky = t / 5;
        const int kx = t - ky * 5;
        const int row = hr + ky;

        short8 bf[4];
        #pragma unroll
        for (int n = 0; n < 4; ++n)
            bf[n] = *(const short8*)&xs[((l4 * 6 + row) * XTH +
                                        (wn * 64 + n * 16 + l15 + kx)) * 8];
        if (t & 1) {
            #pragma unroll
            for (int m = 0; m < 8; ++m)
                #pragma unroll
                for (int n = 0; n < 4; ++n)
                    acc[m][n] = __builtin_amdgcn_mfma_f32_16x16x32_bf16(
                        af1[m], bf[n], acc[m][n], 0, 0, 0);
        } else {
            #pragma unroll
            for (int m = 0; m < 8; ++m)
                #pragma unroll
                for (int n = 0; n < 4; ++n)
                    acc[m][n] = __builtin_amdgcn_mfma_f32_16x16x32_bf16(
                        af0[m], bf[n], acc[m][n], 0, 0, 0);
        }
    }

    // ---- epilogue: leaky relu + store ----
    int h = h0 + hr;
    float* ob = out + ((size_t)b * COTOT_ + cobase) * (HW_ * HW_)
                    + (size_t)h * HW_ + wn * 64;
    #pragma unroll
    for (int m = 0; m < 8; ++m) {
        #pragma unroll
        for (int n = 0; n < 4; ++n) {
            #pragma unroll
            for (int r = 0; r < 4; ++r) {
                int co = m * 16 + l4 * 4 + r;
                int w  = n * 16 + l15;
                float v = acc[m][n][r];
                v = (v >= 0.0f) ? v : 0.01f * v;
                ob[(size_t)co * (HW_ * HW_) + w] = v;
            }
        }
    }
}

extern "C" void kernel_launch(void* const* d_in, const int* in_sizes, int n_in,
                              void* d_out, int out_size, void* d_ws, size_t ws_size,
                              hipStream_t stream) {
    const float* x       = (const float*)d_in[0];
    const float* kernel  = (const float*)d_in[1];
    const float* relaxed = (const float*)d_in[2];
    float* out = (float*)d_out;

    unsigned short* xt = (unsigned short*)d_ws;   // 16*132*132*32*2 = 17,842,176 B
    unsigned short* wt = (unsigned short*)((char*)d_ws + (size_t)B_ * XTH * XTH * IC_ * 2);

    const int xtot = B_ * XTH * XTH;
    xform_kernel<<<(xtot + 255) / 256, 256, 0, stream>>>(x, xt);

    const int wtot = 25 * COTOT_ * IC_;
    build_w_kernel<<<(wtot + 255) / 256, 256, 0, stream>>>(kernel, relaxed, wt);

    dim3 grid(HW_ / 2, B_, COTOT_ / 128);
    conv_mfma_kernel<<<grid, 256, 0, stream>>>(xt, wt, out);
}

// Round 5
// 275.043 us; speedup vs baseline: 1.0322x; 1.0322x over previous
//
#include <hip/hip_runtime.h>
#include <hip/hip_bf16.h>
#include <math.h>

// Problem constants
#define B_   16
#define IC_  32
#define HW_  128
#define NF_  8
#define OC_  64
#define K_   5
#define GRP_ 8
#define COTOT_ (OC_ * GRP_)   // 512
#define XTH  132              // padded spatial (128 + 2*2)
#define TAPSTRIDE (COTOT_ * IC_)   // elements per tap in wt

typedef short  short8  __attribute__((ext_vector_type(8)));
typedef unsigned short ushort8 __attribute__((ext_vector_type(8)));
typedef float  f32x4   __attribute__((ext_vector_type(4)));

static __device__ inline unsigned short f2bf(float f) {
    unsigned u = __builtin_bit_cast(unsigned, f);
    unsigned r = (u + 0x7FFFu + ((u >> 16) & 1u)) >> 16;
    return (unsigned short)r;
}

// async global -> LDS, 16 bytes per lane (dest = uniform base + lane*16)
__device__ __forceinline__ void gload16(void* lds, const void* g) {
    __builtin_amdgcn_global_load_lds(
        (const __attribute__((address_space(1))) unsigned int*)g,
        (__attribute__((address_space(3))) unsigned int*)lds, 16, 0, 0);
}

// ---------------------------------------------------------------------------
// Kernel 1: x NCHW fp32 -> padded NHWC bf16   xt[b][hp][wp][ic]
// ---------------------------------------------------------------------------
__global__ __launch_bounds__(256) void xform_kernel(
    const float* __restrict__ x, unsigned short* __restrict__ xt) {
    int idx = blockIdx.x * blockDim.x + threadIdx.x;
    const int TOT = B_ * XTH * XTH;
    if (idx >= TOT) return;
    int wp = idx % XTH;
    int t  = idx / XTH;
    int hp = t % XTH;
    int b  = t / XTH;

    unsigned short vals[IC_];
    bool interior = (hp >= 2) && (hp < 2 + HW_) && (wp >= 2) && (wp < 2 + HW_);
    if (interior) {
        const float* xb = x + ((size_t)b * IC_) * (HW_ * HW_) + (hp - 2) * HW_ + (wp - 2);
        #pragma unroll
        for (int ic = 0; ic < IC_; ++ic)
            vals[ic] = f2bf(xb[(size_t)ic * (HW_ * HW_)]);
    } else {
        #pragma unroll
        for (int ic = 0; ic < IC_; ++ic) vals[ic] = 0;
    }
    ushort8* dst = (ushort8*)(xt + (size_t)idx * IC_);
    #pragma unroll
    for (int c = 0; c < 4; ++c) {
        ushort8 v;
        #pragma unroll
        for (int j = 0; j < 8; ++j) v[j] = vals[c * 8 + j];
        dst[c] = v;
    }
}

// ---------------------------------------------------------------------------
// Kernel 2: rotated+mixed weights -> bf16, layout wt[tap25][co512][ic32]
// ---------------------------------------------------------------------------
__global__ __launch_bounds__(256) void build_w_kernel(
    const float* __restrict__ kern,
    const float* __restrict__ relaxed,
    unsigned short* __restrict__ wt) {
    int idx = blockIdx.x * blockDim.x + threadIdx.x;
    const int TOT = 25 * COTOT_ * IC_;
    if (idx >= TOT) return;
    int ic = idx & (IC_ - 1);
    int t  = idx >> 5;
    int co = t & (COTOT_ - 1);
    int e  = t >> 9;            // ky*5+kx
    int a  = co & (GRP_ - 1);
    int o  = co >> 3;
    int i  = e / K_;            // ky
    int j  = e - i * K_;        // kx

    float theta = -6.283185307179586f / (float)GRP_ * (float)a;
    float cth = cosf(theta), sth = sinf(theta);
    float bx = (2.0f * (float)j + 1.0f) / (float)K_ - 1.0f;
    float by = (2.0f * (float)i + 1.0f) / (float)K_ - 1.0f;
    float gx = cth * bx - sth * by;
    float gy = sth * bx + cth * by;
    float ix = ((gx + 1.0f) * (float)K_ - 1.0f) * 0.5f;
    float iy = ((gy + 1.0f) * (float)K_ - 1.0f) * 0.5f;
    float x0 = floorf(ix), y0 = floorf(iy);
    float wx1 = ix - x0, wy1 = iy - y0;
    float wx0 = 1.0f - wx1, wy0 = 1.0f - wy1;

    float xs2[2]  = {x0, x0 + 1.0f};
    float ys2[2]  = {y0, y0 + 1.0f};
    float wxs[2] = {wx0, wx1};
    float wys[2] = {wy0, wy1};

    float tw[4];
    int   tyc[4], txc[4];
    #pragma unroll
    for (int dy = 0; dy < 2; ++dy) {
        #pragma unroll
        for (int dx = 0; dx < 2; ++dx) {
            float xx = xs2[dx], yy = ys2[dy];
            bool valid = (xx >= 0.0f) && (xx < (float)K_) &&
                         (yy >= 0.0f) && (yy < (float)K_);
            int tp = dy * 2 + dx;
            tw[tp]  = wys[dy] * wxs[dx] * (valid ? 1.0f : 0.0f);
            txc[tp] = (int)fminf(fmaxf(xx, 0.0f), (float)(K_ - 1));
            tyc[tp] = (int)fminf(fmaxf(yy, 0.0f), (float)(K_ - 1));
        }
    }

    float acc = 0.0f;
    #pragma unroll
    for (int n = 0; n < NF_; ++n) {
        const float* kb = kern + ((size_t)((n * OC_ + o) * IC_ + ic)) * (K_ * K_);
        float v = 0.0f;
        #pragma unroll
        for (int tp = 0; tp < 4; ++tp)
            v += kb[tyc[tp] * K_ + txc[tp]] * tw[tp];
        acc += relaxed[n * GRP_ + a] * v;
    }
    wt[idx] = f2bf(acc);
}

// ---------------------------------------------------------------------------
// Kernel 3: MFMA implicit-GEMM conv + leaky relu
// block = 256 thr (4 waves) = 128 co x 2 h x 128 w
// wave  = 8x4 fragments of 16x16: 128 co x 64 w at one h row
// xs = verbatim copy of xt rows h0..h0+5 ([row][w][ic32]) -> conflict-free
//      b128 reads (wave reads a permutation of one contiguous 1 KB).
// Weights: global -> VGPR, register double-buffer with static names,
//          tap-pair loop (#pragma unroll 1) -> counted vmcnt, no hoist-chaos.
// ---------------------------------------------------------------------------
__global__ __launch_bounds__(256, 2) void conv_mfma_kernel(
    const unsigned short* __restrict__ xt,
    const unsigned short* __restrict__ wt,
    float* __restrict__ out) {
    // 6 rows x 132 w x 32 ic bf16 = 50688 B, exact copy of xt slab
    __shared__ __align__(16) unsigned short xs[6 * XTH * IC_];

    int tid  = threadIdx.x;
    int lane = tid & 63;
    int wv   = tid >> 6;          // 0..3
    int l15  = lane & 15;
    int l4   = lane >> 4;         // 0..3 (k-chunk)
    int hr   = wv >> 1;           // wave's output row (0/1)
    int wn   = wv & 1;            // wave's w half (0/1)

    int hp = blockIdx.x;          // 0..63 -> rows 2*hp, 2*hp+1
    int b  = blockIdx.y;
    int cg = blockIdx.z;          // slowest: same-cg blocks cluster in time
    int cobase = cg * 128;
    int h0 = hp * 2;

    // ---- stage x slab once (async, purely linear: src and dest contiguous) ----
    {
        const unsigned short* xb = xt + (((size_t)b * XTH + h0) * XTH) * IC_;
        #pragma unroll
        for (int i = 0; i < 13; ++i) {
            int s = i * 256 + tid;          // 16B slots, 3168 total
            if (s < 3168) gload16(&xs[s * 8], xb + (size_t)s * 8);
        }
    }

    // per-lane weight base: co = cobase + m*16 + l15, k = l4*8..
    const unsigned short* wl = wt + (size_t)(cobase + l15) * IC_ + l4 * 8;

    // ---- preload tap 0 weights into afA ----
    short8 afA[8], afB[8];
    #pragma unroll
    for (int m = 0; m < 8; ++m)
        afA[m] = *(const short8*)(wl + (size_t)m * 16 * IC_);

    f32x4 acc[8][4];
    #pragma unroll
    for (int m = 0; m < 8; ++m)
        #pragma unroll
        for (int n = 0; n < 4; ++n) acc[m][n] = (f32x4)(0.0f);

    __syncthreads();   // x slab visible to all waves (drains vmcnt too)

    // byte offset into xs for this wave at tap (ky=0,kx=0)
    const char* xsb = (const char*)xs;
    int xoff = (hr * XTH + wn * 64 + l15) * 64 + l4 * 16;
    int kx = 0;

    #pragma unroll 1
    for (int pi = 0; pi < 12; ++pi) {
        int t0 = pi * 2;
        // ---- prefetch tap t0+1 -> afB ----
        {
            const unsigned short* wp = wl + (size_t)(t0 + 1) * TAPSTRIDE;
            #pragma unroll
            for (int m = 0; m < 8; ++m)
                afB[m] = *(const short8*)(wp + (size_t)m * 16 * IC_);
        }
        // ---- compute tap t0 with afA ----
        {
            short8 bf[4];
            #pragma unroll
            for (int n = 0; n < 4; ++n)
                bf[n] = *(const short8*)(xsb + xoff + n * 1024);
            __builtin_amdgcn_s_setprio(1);
            #pragma unroll
            for (int m = 0; m < 8; ++m)
                #pragma unroll
                for (int n = 0; n < 4; ++n)
                    acc[m][n] = __builtin_amdgcn_mfma_f32_16x16x32_bf16(
                        afA[m], bf[n], acc[m][n], 0, 0, 0);
            __builtin_amdgcn_s_setprio(0);
        }
        if (++kx == 5) { kx = 0; xoff += 8192; } else { xoff += 64; }

        // ---- prefetch tap t0+2 -> afA ----
        {
            const unsigned short* wp = wl + (size_t)(t0 + 2) * TAPSTRIDE;
            #pragma unroll
            for (int m = 0; m < 8; ++m)
                afA[m] = *(const short8*)(wp + (size_t)m * 16 * IC_);
        }
        // ---- compute tap t0+1 with afB ----
        {
            short8 bf[4];
            #pragma unroll
            for (int n = 0; n < 4; ++n)
                bf[n] = *(const short8*)(xsb + xoff + n * 1024);
            __builtin_amdgcn_s_setprio(1);
            #pragma unroll
            for (int m = 0; m < 8; ++m)
                #pragma unroll
                for (int n = 0; n < 4; ++n)
                    acc[m][n] = __builtin_amdgcn_mfma_f32_16x16x32_bf16(
                        afB[m], bf[n], acc[m][n], 0, 0, 0);
            __builtin_amdgcn_s_setprio(0);
        }
        if (++kx == 5) { kx = 0; xoff += 8192; } else { xoff += 64; }
    }
    // ---- tail: tap 24 with afA ----
    {
        short8 bf[4];
        #pragma unroll
        for (int n = 0; n < 4; ++n)
            bf[n] = *(const short8*)(xsb + xoff + n * 1024);
        __builtin_amdgcn_s_setprio(1);
        #pragma unroll
        for (int m = 0; m < 8; ++m)
            #pragma unroll
            for (int n = 0; n < 4; ++n)
                acc[m][n] = __builtin_amdgcn_mfma_f32_16x16x32_bf16(
                    afA[m], bf[n], acc[m][n], 0, 0, 0);
        __builtin_amdgcn_s_setprio(0);
    }

    // ---- epilogue: leaky relu + store ----
    int h = h0 + hr;
    float* ob = out + ((size_t)b * COTOT_ + cobase) * (HW_ * HW_)
                    + (size_t)h * HW_ + wn * 64;
    #pragma unroll
    for (int m = 0; m < 8; ++m) {
        #pragma unroll
        for (int n = 0; n < 4; ++n) {
            #pragma unroll
            for (int r = 0; r < 4; ++r) {
                int co = m * 16 + l4 * 4 + r;
                int w  = n * 16 + l15;
                float v = acc[m][n][r];
                v = (v >= 0.0f) ? v : 0.01f * v;
                ob[(size_t)co * (HW_ * HW_) + w] = v;
            }
        }
    }
}

extern "C" void kernel_launch(void* const* d_in, const int* in_sizes, int n_in,
                              void* d_out, int out_size, void* d_ws, size_t ws_size,
                              hipStream_t stream) {
    const float* x       = (const float*)d_in[0];
    const float* kernel  = (const float*)d_in[1];
    const float* relaxed = (const float*)d_in[2];
    float* out = (float*)d_out;

    unsigned short* xt = (unsigned short*)d_ws;   // 16*132*132*32*2 = 17,842,176 B
    unsigned short* wt = (unsigned short*)((char*)d_ws + (size_t)B_ * XTH * XTH * IC_ * 2);

    const int xtot = B_ * XTH * XTH;
    xform_kernel<<<(xtot + 255) / 256, 256, 0, stream>>>(x, xt);

    const int wtot = 25 * COTOT_ * IC_;
    build_w_kernel<<<(wtot + 255) / 256, 256, 0, stream>>>(kernel, relaxed, wt);

    dim3 grid(HW_ / 2, B_, COTOT_ / 128);
    conv_mfma_kernel<<<grid, 256, 0, stream>>>(xt, wt, out);
}